// Round 18
// baseline (472.218 us; speedup 1.0000x reference)
//
#include <hip/hip_runtime.h>

#define BATCH 100000
#define M3 300000            // 3*BATCH rows
#define VECBASE 51200000     // BATCH*512 floats; start of vectors_out region in d_out
#define KP 704               // padded K for Ab/WfT (656 -> 11*64)

typedef float fl4  __attribute__((ext_vector_type(4)));
typedef float f32x4 __attribute__((ext_vector_type(4)));
typedef short s16x4 __attribute__((ext_vector_type(4)));
typedef short s16x8 __attribute__((ext_vector_type(8)));

__device__ __forceinline__ short f2bf(float f) {
  unsigned int u = __float_as_uint(f);
  u += 0x7fffu + ((u >> 16) & 1u);
  return (short)(u >> 16);
}
__device__ __forceinline__ float bf2f(short s) {
  return __uint_as_float(((unsigned int)(unsigned short)s) << 16);
}
__device__ __forceinline__ s16x8 pack8(fl4 a, fl4 b) {
  s16x8 o;
  o[0] = f2bf(a[0]); o[1] = f2bf(a[1]); o[2] = f2bf(a[2]); o[3] = f2bf(a[3]);
  o[4] = f2bf(b[0]); o[5] = f2bf(b[1]); o[6] = f2bf(b[2]); o[7] = f2bf(b[3]);
  return o;
}
__device__ __forceinline__ void glds16(const void* g, void* l) {
  __builtin_amdgcn_global_load_lds((const __attribute__((address_space(1))) void*)g,
                                   (__attribute__((address_space(3))) void*)l, 16, 0, 0);
}

// ---------------------------------------------------------------------------
// K0: prep — weight transposes only.
__global__ __launch_bounds__(256) void prep_w(
    const float* __restrict__ Wh, const float* __restrict__ Wcp,
    const float* __restrict__ Wu, const float* __restrict__ Wf,
    const float* __restrict__ Wg, short* __restrict__ WB1,
    short* __restrict__ WuTp, short* __restrict__ WfT, short* __restrict__ WgT) {
  int gid = blockIdx.x * 256 + threadIdx.x;
  if (gid < 20480) {                       // WB1 [160][128]
    int n = gid >> 7, k = gid & 127;
    WB1[gid] = f2bf(n < 128 ? Wh[k * 128 + n] : Wcp[k * 32 + (n - 128)]);
  } else if (gid < 40960) {                // WuTp [128][160]
    int i = gid - 20480;
    int o = i / 160, k = i - o * 160;
    WuTp[i] = k < 144 ? f2bf(Wu[k * 128 + o]) : (short)0;
  } else if (gid < 401408) {               // WfT [512][704]
    int i = gid - 40960;
    int n = i / KP, k = i - n * KP;
    WfT[i] = k < 656 ? f2bf(Wf[k * 512 + n]) : (short)0;
  } else if (gid < 466944) {               // WgT [128][512]
    int i = gid - 401408;
    int n = i >> 9, k = i & 511;
    WgT[i] = f2bf(Wg[k * 128 + n]);
  }
}

// ---------------------------------------------------------------------------
// K1: geo_fused (R17-exact): GEMM1 + cross + norms->Ab + GEMM2->Vub + feats->Ab.
__global__ __launch_bounds__(256) void geo_fused(
    const float* __restrict__ vecs, const float* __restrict__ feats,
    const short* __restrict__ WB1, const short* __restrict__ WuTp,
    short* __restrict__ Ab, short* __restrict__ Vub) {
  __shared__ __align__(16) short U[96 * 168];
  const int t = threadIdx.x;
  const int b0 = blockIdx.x * 32;
  const int row0 = blockIdx.x * 96;

#pragma unroll
  for (int it = 0; it < 4; ++it) {
    int fi = (it * 256 + t) * 12;
    int bl = fi / 384;
    int rem = fi - bl * 384;
    int v0 = rem / 3;
    const float* p = &vecs[(size_t)(b0 + bl) * 384 + rem];
    fl4 x = *(const fl4*)p, y = *(const fl4*)(p + 4), z = *(const fl4*)(p + 8);
    float vc[3][4] = {{x[0], x[3], y[2], z[1]},
                      {x[1], y[0], y[3], z[2]},
                      {x[2], y[1], z[0], z[3]}};
#pragma unroll
    for (int c = 0; c < 3; ++c) {
      int row = bl * 3 + c;
      s16x4 q;
#pragma unroll
      for (int e = 0; e < 4; ++e) q[e] = f2bf(vc[c][e]);
      int off = (row << 8) + (v0 << 1);
      *(s16x4*)((char*)U + (off ^ ((row & 7) << 4))) = q;
    }
  }
  __syncthreads();

  const int lane = t & 63, wv = t >> 6;
  const int wr = wv >> 1, wc = wv & 1;
  const int lr = lane & 15, lk = lane >> 4;

  {  // GEMM1: per wave 48x80, acc[3][5]
    f32x4 acc[3][5];
#pragma unroll
    for (int i = 0; i < 3; ++i)
#pragma unroll
      for (int j = 0; j < 5; ++j) acc[i][j] = (f32x4){0.f, 0.f, 0.f, 0.f};
#pragma unroll
    for (int kk = 0; kk < 4; ++kk) {
      s16x8 af[3], bq[5];
#pragma unroll
      for (int mi = 0; mi < 3; ++mi) {
        int row = wr * 48 + mi * 16 + lr;
        int off = (row << 8) + (kk << 6) + (lk << 4);
        af[mi] = *(const s16x8*)((const char*)U + (off ^ ((row & 7) << 4)));
      }
#pragma unroll
      for (int ni = 0; ni < 5; ++ni)
        bq[ni] = *reinterpret_cast<const s16x8*>(
            &WB1[(wc * 80 + ni * 16 + lr) * 128 + (kk << 5) + (lk << 3)]);
      __builtin_amdgcn_s_setprio(1);
#pragma unroll
      for (int mi = 0; mi < 3; ++mi)
#pragma unroll
        for (int ni = 0; ni < 5; ++ni)
          acc[mi][ni] = __builtin_amdgcn_mfma_f32_16x16x32_bf16(af[mi], bq[ni], acc[mi][ni], 0, 0, 0);
      __builtin_amdgcn_s_setprio(0);
    }
    __syncthreads();
#pragma unroll
    for (int mi = 0; mi < 3; ++mi)
#pragma unroll
      for (int ni = 0; ni < 5; ++ni) {
        int col = wc * 80 + ni * 16 + lr;
#pragma unroll
        for (int r = 0; r < 4; ++r) {
          int row = wr * 48 + mi * 16 + lk * 4 + r;
          U[row * 168 + col] = f2bf(acc[mi][ni][r]);
        }
      }
  }
  __syncthreads();

  {  // cross: 8 threads per b, 2 p's each
    int bl = t >> 3, pj = t & 7;
    int gb = b0 + bl;
    float shcp[2];
#pragma unroll
    for (int q = 0; q < 2; ++q) {
      int p = pj * 2 + q;
      float ax = bf2f(U[(bl * 3 + 0) * 168 + 128 + p]);
      float ay = bf2f(U[(bl * 3 + 1) * 168 + 128 + p]);
      float az = bf2f(U[(bl * 3 + 2) * 168 + 128 + p]);
      float bx = bf2f(U[(bl * 3 + 0) * 168 + 144 + p]);
      float by = bf2f(U[(bl * 3 + 1) * 168 + 144 + p]);
      float bz = bf2f(U[(bl * 3 + 2) * 168 + 144 + p]);
      float cx = ay * bz - az * by;
      float cy = az * bx - ax * bz;
      float cz = ax * by - ay * bx;
      U[(bl * 3 + 0) * 168 + 128 + p] = f2bf(cx);
      U[(bl * 3 + 1) * 168 + 128 + p] = f2bf(cy);
      U[(bl * 3 + 2) * 168 + 128 + p] = f2bf(cz);
      U[(bl * 3 + 0) * 168 + 144 + p] = 0;
      U[(bl * 3 + 1) * 168 + 144 + p] = 0;
      U[(bl * 3 + 2) * 168 + 144 + p] = 0;
      shcp[q] = sqrtf(fmaxf(cx * cx + cy * cy + cz * cz, 1e-8f));
    }
    Ab[(size_t)gb * KP + 640 + pj * 2]     = f2bf(shcp[0]);
    Ab[(size_t)gb * KP + 640 + pj * 2 + 1] = f2bf(shcp[1]);
#pragma unroll
    for (int z = 0; z < 6; ++z)
      Ab[(size_t)gb * KP + 656 + pj * 6 + z] = 0;
  }
  {  // norms k<128 -> Ab cols 512..639
    int bl = t >> 3, kq = t & 7;
    int gb = b0 + bl;
#pragma unroll
    for (int j = 0; j < 2; ++j) {
      int k = kq * 16 + j * 8;
      s16x8 r0 = *(const s16x8*)&U[(bl * 3 + 0) * 168 + k];
      s16x8 r1 = *(const s16x8*)&U[(bl * 3 + 1) * 168 + k];
      s16x8 r2 = *(const s16x8*)&U[(bl * 3 + 2) * 168 + k];
      s16x8 o;
#pragma unroll
      for (int e = 0; e < 8; ++e) {
        float x = bf2f(r0[e]), y = bf2f(r1[e]), z = bf2f(r2[e]);
        o[e] = f2bf(sqrtf(fmaxf(x * x + y * y + z * z, 1e-8f)));
      }
      *(s16x8*)&Ab[(size_t)gb * KP + 512 + k] = o;
    }
  }
  __syncthreads();

  {  // GEMM2: per wave 48x64, acc[3][4]
    f32x4 acc2[3][4];
#pragma unroll
    for (int i = 0; i < 3; ++i)
#pragma unroll
      for (int j = 0; j < 4; ++j) acc2[i][j] = (f32x4){0.f, 0.f, 0.f, 0.f};
#pragma unroll
    for (int kk = 0; kk < 5; ++kk) {
      s16x8 af[3], bq[4];
#pragma unroll
      for (int mi = 0; mi < 3; ++mi) {
        int row = wr * 48 + mi * 16 + lr;
        af[mi] = *(const s16x8*)&U[row * 168 + (kk << 5) + (lk << 3)];
      }
#pragma unroll
      for (int ni = 0; ni < 4; ++ni)
        bq[ni] = *reinterpret_cast<const s16x8*>(
            &WuTp[(wc * 64 + ni * 16 + lr) * 160 + (kk << 5) + (lk << 3)]);
      __builtin_amdgcn_s_setprio(1);
#pragma unroll
      for (int mi = 0; mi < 3; ++mi)
#pragma unroll
        for (int ni = 0; ni < 4; ++ni)
          acc2[mi][ni] = __builtin_amdgcn_mfma_f32_16x16x32_bf16(af[mi], bq[ni], acc2[mi][ni], 0, 0, 0);
      __builtin_amdgcn_s_setprio(0);
    }
#pragma unroll
    for (int mi = 0; mi < 3; ++mi)
#pragma unroll
      for (int ni = 0; ni < 4; ++ni) {
        int col = wc * 64 + ni * 16 + lr;
#pragma unroll
        for (int r = 0; r < 4; ++r) {
          int row = row0 + wr * 48 + mi * 16 + lk * 4 + r;
          Vub[(size_t)row * 128 + col] = f2bf(acc2[mi][ni][r]);
        }
      }
  }

  {  // feats -> Ab[:,0:512) bf16 for this block's 32 rows
#pragma unroll
    for (int j = 0; j < 8; ++j) {
      int idx = j * 256 + t;
      int bl = idx >> 6, kk = (idx & 63) * 8;
      const float* p = &feats[(size_t)(b0 + bl) * 512 + kk];
      fl4 v0 = *(const fl4*)p, v1 = *(const fl4*)(p + 4);
      *(s16x8*)&Ab[(size_t)(b0 + bl) * KP + kk] = pack8(v0, v1);
    }
  }
}

// ---------------------------------------------------------------------------
// K2: feats_out = silu(Ab @ Wf + bf) -> out f32 + fob bf16.
// 1024 threads, 256x256 tile (4x4 waves, per-wave 64x64), BK=64 single-buffered.
// 64KB LDS -> 2 blocks/CU = 32 waves/CU (8/SIMD, max TLP); 512 MFMA per
// barrier-pair per block (2x R16 amortization). Grid 782, bijective XCD remap.
__global__ __launch_bounds__(1024, 2) void gemm_feats(
    const short* __restrict__ Ab, const short* __restrict__ WfT,
    const float* __restrict__ bfv, float* __restrict__ out,
    short* __restrict__ fob) {
  const int bid = blockIdx.x;
  const int xcd = bid & 7, bi = bid >> 3;   // 782 = 8*97 + 6
  const int swz = (xcd < 6 ? xcd * 98 : 588 + (xcd - 6) * 97) + bi;
  const int mt = swz >> 1, nt = swz & 1;
  const int row0 = mt << 8, n0 = nt << 8;
  const int t = threadIdx.x;
  const int lane = t & 63, wv = t >> 6;     // 16 waves
  const int wr = wv >> 2, wc = wv & 3;      // 4 x 4 wave grid
  const int lr = lane & 15, lk = lane >> 4;

  __shared__ __align__(16) short S[(256 + 256) * 64];   // 64 KB: As | Bs
  short* As = S;                  // [256][64]
  short* Bs = S + 256 * 64;       // [256][64]

  // A: 2048 chunks (256 rows x 8), 2/thread; B same
  const short* srcA[2]; int adof[2];
#pragma unroll
  for (int j = 0; j < 2; ++j) {
    int cid = j * 1024 + t;
    int row = cid >> 3, ch = cid & 7;
    srcA[j] = &Ab[(size_t)min(row0 + row, BATCH - 1) * KP + (ch ^ (row & 7)) * 8];
    adof[j] = cid * 8;
  }
  const short* srcB[2]; int bdof[2];
#pragma unroll
  for (int j = 0; j < 2; ++j) {
    int cid = j * 1024 + t;
    int row = cid >> 3, ch = cid & 7;
    srcB[j] = &WfT[(size_t)(n0 + row) * KP + (ch ^ (row & 7)) * 8];
    bdof[j] = cid * 8;
  }

  f32x4 acc[4][4];
#pragma unroll
  for (int i = 0; i < 4; ++i)
#pragma unroll
    for (int j = 0; j < 4; ++j) acc[i][j] = (f32x4){0.f, 0.f, 0.f, 0.f};

  for (int ks = 0; ks < 11; ++ks) {
    const int k0 = ks << 6;
    __syncthreads();
    glds16(srcA[0] + k0, &As[adof[0]]);
    glds16(srcA[1] + k0, &As[adof[1]]);
    glds16(srcB[0] + k0, &Bs[bdof[0]]);
    glds16(srcB[1] + k0, &Bs[bdof[1]]);
    __syncthreads();
#pragma unroll
    for (int kk = 0; kk < 2; ++kk) {
      s16x8 af[4], bq[4];
#pragma unroll
      for (int mi = 0; mi < 4; ++mi) {
        int rw = wr * 64 + mi * 16 + lr;
        af[mi] = *(const s16x8*)&As[rw * 64 + (((kk << 2) + lk) ^ (rw & 7)) * 8];
      }
#pragma unroll
      for (int ni = 0; ni < 4; ++ni) {
        int rn = wc * 64 + ni * 16 + lr;
        bq[ni] = *(const s16x8*)&Bs[rn * 64 + (((kk << 2) + lk) ^ (rn & 7)) * 8];
      }
      __builtin_amdgcn_s_setprio(1);
#pragma unroll
      for (int mi = 0; mi < 4; ++mi)
#pragma unroll
        for (int ni = 0; ni < 4; ++ni)
          acc[mi][ni] = __builtin_amdgcn_mfma_f32_16x16x32_bf16(af[mi], bq[ni], acc[mi][ni], 0, 0, 0);
      __builtin_amdgcn_s_setprio(0);
    }
  }

  // coalesced epilogue: 8 groups of 32 rows staged through LDS (32KB of S)
  float* Ls = (float*)S;
#pragma unroll
  for (int g = 0; g < 8; ++g) {
    __syncthreads();
    if (wr == (g >> 1)) {
      int miB = (g & 1) * 2;
#pragma unroll
      for (int m2 = 0; m2 < 2; ++m2) {
#pragma unroll
        for (int ni = 0; ni < 4; ++ni) {
          int colL = wc * 64 + ni * 16 + lr;
          float bb = bfv[n0 + colL];
#pragma unroll
          for (int rr = 0; rr < 4; ++rr) {
            int rowL = m2 * 16 + lk * 4 + rr;
            float x = acc[miB + m2][ni][rr] + bb;
            Ls[rowL * 256 + colL] = x / (1.f + __expf(-x));
          }
        }
      }
    }
    __syncthreads();
    {
      int rowL = t >> 5, seg = t & 31;      // 32 rows, 32 thr/row, 8 f32 each
      int grow = row0 + g * 32 + rowL;
      if (grow < BATCH) {
        const float* p = &Ls[rowL * 256 + seg * 8];
        fl4 a = *(const fl4*)p, b = *(const fl4*)(p + 4);
        float* po = &out[(size_t)grow * 512 + n0 + seg * 8];
        *(fl4*)po = a; *(fl4*)(po + 4) = b;
        *(s16x8*)&fob[(size_t)grow * 512 + n0 + seg * 8] = pack8(a, b);
      }
    }
  }
}

// ---------------------------------------------------------------------------
// K3: gating GEMM + sigmoid*Vub -> vectors_out f32. (R16-exact)
__global__ __launch_bounds__(512, 4) void gemm_gate(
    const short* __restrict__ fob, const short* __restrict__ WgT,
    const float* __restrict__ bg, const short* __restrict__ Vub,
    float* __restrict__ out) {
  const int bid = blockIdx.x;
  const int xcd = bid & 7, bi = bid >> 3;
  const int swz = (xcd < 7 ? xcd * 49 : 343 + (xcd - 7) * 48) + bi;
  const int row0 = swz << 8;
  const int t = threadIdx.x;
  const int lane = t & 63, wv = t >> 6;
  const int wr = wv >> 1, wc = wv & 1;
  const int lr = lane & 15, lk = lane >> 4;

  __shared__ __align__(16) short S[(256 + 128) * 64];
  short* As = S;
  short* Bs = S + 256 * 64;

  const short* srcA[4]; int adof[4];
#pragma unroll
  for (int j = 0; j < 4; ++j) {
    int cid = j * 512 + t;
    int row = cid >> 3, ch = cid & 7;
    srcA[j] = &fob[(size_t)min(row0 + row, BATCH - 1) * 512 + (ch ^ (row & 7)) * 8];
    adof[j] = cid * 8;
  }
  const short* srcB[2]; int bdof[2];
#pragma unroll
  for (int j = 0; j < 2; ++j) {
    int cid = j * 512 + t;
    int row = cid >> 3, ch = cid & 7;
    srcB[j] = &WgT[(size_t)row * 512 + (ch ^ (row & 7)) * 8];
    bdof[j] = cid * 8;
  }

  f32x4 acc[4][4];
#pragma unroll
  for (int i = 0; i < 4; ++i)
#pragma unroll
    for (int j = 0; j < 4; ++j) acc[i][j] = (f32x4){0.f, 0.f, 0.f, 0.f};

  for (int ks = 0; ks < 8; ++ks) {
    const int k0 = ks << 6;
    __syncthreads();
#pragma unroll
    for (int j = 0; j < 4; ++j) glds16(srcA[j] + k0, &As[adof[j]]);
    glds16(srcB[0] + k0, &Bs[bdof[0]]);
    glds16(srcB[1] + k0, &Bs[bdof[1]]);
    __syncthreads();
#pragma unroll
    for (int kk = 0; kk < 2; ++kk) {
      s16x8 af[4], bq[4];
#pragma unroll
      for (int mi = 0; mi < 4; ++mi) {
        int rw = wr * 64 + mi * 16 + lr;
        af[mi] = *(const s16x8*)&As[rw * 64 + (((kk << 2) + lk) ^ (rw & 7)) * 8];
      }
#pragma unroll
      for (int ni = 0; ni < 4; ++ni) {
        int rn = wc * 64 + ni * 16 + lr;
        bq[ni] = *(const s16x8*)&Bs[rn * 64 + (((kk << 2) + lk) ^ (rn & 7)) * 8];
      }
      __builtin_amdgcn_s_setprio(1);
#pragma unroll
      for (int mi = 0; mi < 4; ++mi)
#pragma unroll
        for (int ni = 0; ni < 4; ++ni)
          acc[mi][ni] = __builtin_amdgcn_mfma_f32_16x16x32_bf16(af[mi], bq[ni], acc[mi][ni], 0, 0, 0);
      __builtin_amdgcn_s_setprio(0);
    }
  }

#pragma unroll
  for (int ni = 0; ni < 4; ++ni) {
    int col = wc * 64 + ni * 16 + lr;
    float bb = bg[col];
#pragma unroll
    for (int mi = 0; mi < 4; ++mi) {
      int rbase = row0 + wr * 64 + mi * 16 + lk * 4;
#pragma unroll
      for (int rr = 0; rr < 4; ++rr) {
        int gr = rbase + rr;
        if (gr < BATCH) {
          float x = acc[mi][ni][rr] + bb;
          float gate = 1.f / (1.f + __expf(-x));
          size_t vb = (size_t)(3 * gr) * 128 + col;
          float* po = &out[VECBASE + ((size_t)gr * 128 + col) * 3];
          po[0] = gate * bf2f(Vub[vb]);
          po[1] = gate * bf2f(Vub[vb + 128]);
          po[2] = gate * bf2f(Vub[vb + 256]);
        }
      }
    }
  }
}

// ---------------------------------------------------------------------------
extern "C" void kernel_launch(void* const* d_in, const int* in_sizes, int n_in,
                              void* d_out, int out_size, void* d_ws, size_t ws_size,
                              hipStream_t stream) {
  const float* feats = (const float*)d_in[0];
  const float* vecs  = (const float*)d_in[1];
  const float* Wh    = (const float*)d_in[2];
  const float* Wcp   = (const float*)d_in[3];
  const float* Wu    = (const float*)d_in[4];
  const float* Wf    = (const float*)d_in[5];
  const float* bfv   = (const float*)d_in[6];
  const float* Wg    = (const float*)d_in[7];
  const float* bg    = (const float*)d_in[8];
  float* out = (float*)d_out;

  char* ws = (char*)d_ws;
  short* Ab   = (short*)ws;                                // 140,800,000 B
  short* Vub  = (short*)(ws + 140800000);                  //  76,800,000 B
  short* fob  = (short*)(ws + 217600000);                  // 102,400,000 B
  short* WfT  = (short*)(ws + 320000000);                  //     720,896 B
  short* WgT  = (short*)(ws + 320720896);                  //     131,072 B
  short* WB1  = (short*)(ws + 320851968);                  //      40,960 B
  short* WuTp = (short*)(ws + 320892928);                  //      40,960 B

  hipLaunchKernelGGL(prep_w,     dim3(1824), dim3(256), 0, stream,
                     Wh, Wcp, Wu, Wf, Wg, WB1, WuTp, WfT, WgT);
  hipLaunchKernelGGL(geo_fused,  dim3(3125), dim3(256), 0, stream,
                     vecs, feats, WB1, WuTp, Ab, Vub);
  hipLaunchKernelGGL(gemm_feats, dim3(782),  dim3(1024), 0, stream,
                     Ab, WfT, bfv, out, fob);
  hipLaunchKernelGGL(gemm_gate,  dim3(391),  dim3(512), 0, stream,
                     fob, WgT, bg, Vub, out);
}

// Round 19
// 422.839 us; speedup vs baseline: 1.1168x; 1.1168x over previous
//
#include <hip/hip_runtime.h>

#define BATCH 100000
#define M3 300000            // 3*BATCH rows
#define VECBASE 51200000     // BATCH*512 floats; start of vectors_out region in d_out
#define KP 704               // padded K for Ab/WfT (656 -> 11*64)

typedef float fl4  __attribute__((ext_vector_type(4)));
typedef float f32x4 __attribute__((ext_vector_type(4)));
typedef short s16x4 __attribute__((ext_vector_type(4)));
typedef short s16x8 __attribute__((ext_vector_type(8)));

__device__ __forceinline__ short f2bf(float f) {
  unsigned int u = __float_as_uint(f);
  u += 0x7fffu + ((u >> 16) & 1u);
  return (short)(u >> 16);
}
__device__ __forceinline__ float bf2f(short s) {
  return __uint_as_float(((unsigned int)(unsigned short)s) << 16);
}
__device__ __forceinline__ s16x8 pack8(fl4 a, fl4 b) {
  s16x8 o;
  o[0] = f2bf(a[0]); o[1] = f2bf(a[1]); o[2] = f2bf(a[2]); o[3] = f2bf(a[3]);
  o[4] = f2bf(b[0]); o[5] = f2bf(b[1]); o[6] = f2bf(b[2]); o[7] = f2bf(b[3]);
  return o;
}
__device__ __forceinline__ void glds16(const void* g, void* l) {
  __builtin_amdgcn_global_load_lds((const __attribute__((address_space(1))) void*)g,
                                   (__attribute__((address_space(3))) void*)l, 16, 0, 0);
}

// ---------------------------------------------------------------------------
// K0: prep — weight transposes only (feats conversion fused into geo_fused).
__global__ __launch_bounds__(256) void prep_w(
    const float* __restrict__ Wh, const float* __restrict__ Wcp,
    const float* __restrict__ Wu, const float* __restrict__ Wf,
    const float* __restrict__ Wg, short* __restrict__ WB1,
    short* __restrict__ WuTp, short* __restrict__ WfT, short* __restrict__ WgT) {
  int gid = blockIdx.x * 256 + threadIdx.x;
  if (gid < 20480) {                       // WB1 [160][128]
    int n = gid >> 7, k = gid & 127;
    WB1[gid] = f2bf(n < 128 ? Wh[k * 128 + n] : Wcp[k * 32 + (n - 128)]);
  } else if (gid < 40960) {                // WuTp [128][160]
    int i = gid - 20480;
    int o = i / 160, k = i - o * 160;
    WuTp[i] = k < 144 ? f2bf(Wu[k * 128 + o]) : (short)0;
  } else if (gid < 401408) {               // WfT [512][704]
    int i = gid - 40960;
    int n = i / KP, k = i - n * KP;
    WfT[i] = k < 656 ? f2bf(Wf[k * 512 + n]) : (short)0;
  } else if (gid < 466944) {               // WgT [128][512]
    int i = gid - 401408;
    int n = i >> 9, k = i & 511;
    WgT[i] = f2bf(Wg[k * 128 + n]);
  }
}

// ---------------------------------------------------------------------------
// K1: geo_fused, 32 b's (96 rows) per block, 4 blocks/CU.
// GEMM1 + cross + norms->Ab(cols 512..703) + GEMM2->Vub, PLUS the feats->Ab
// bf16 conversion for this block's 32 rows (overlaps geo's BW slack).
__global__ __launch_bounds__(256) void geo_fused(
    const float* __restrict__ vecs, const float* __restrict__ feats,
    const short* __restrict__ WB1, const short* __restrict__ WuTp,
    short* __restrict__ Ab, short* __restrict__ Vub) {
  __shared__ __align__(16) short U[96 * 168];
  const int t = threadIdx.x;
  const int b0 = blockIdx.x * 32;
  const int row0 = blockIdx.x * 96;

#pragma unroll
  for (int it = 0; it < 4; ++it) {
    int fi = (it * 256 + t) * 12;
    int bl = fi / 384;
    int rem = fi - bl * 384;
    int v0 = rem / 3;
    const float* p = &vecs[(size_t)(b0 + bl) * 384 + rem];
    fl4 x = *(const fl4*)p, y = *(const fl4*)(p + 4), z = *(const fl4*)(p + 8);
    float vc[3][4] = {{x[0], x[3], y[2], z[1]},
                      {x[1], y[0], y[3], z[2]},
                      {x[2], y[1], z[0], z[3]}};
#pragma unroll
    for (int c = 0; c < 3; ++c) {
      int row = bl * 3 + c;
      s16x4 q;
#pragma unroll
      for (int e = 0; e < 4; ++e) q[e] = f2bf(vc[c][e]);
      int off = (row << 8) + (v0 << 1);
      *(s16x4*)((char*)U + (off ^ ((row & 7) << 4))) = q;
    }
  }
  __syncthreads();

  const int lane = t & 63, wv = t >> 6;
  const int wr = wv >> 1, wc = wv & 1;
  const int lr = lane & 15, lk = lane >> 4;

  {  // GEMM1: per wave 48x80, acc[3][5]
    f32x4 acc[3][5];
#pragma unroll
    for (int i = 0; i < 3; ++i)
#pragma unroll
      for (int j = 0; j < 5; ++j) acc[i][j] = (f32x4){0.f, 0.f, 0.f, 0.f};
#pragma unroll
    for (int kk = 0; kk < 4; ++kk) {
      s16x8 af[3], bq[5];
#pragma unroll
      for (int mi = 0; mi < 3; ++mi) {
        int row = wr * 48 + mi * 16 + lr;
        int off = (row << 8) + (kk << 6) + (lk << 4);
        af[mi] = *(const s16x8*)((const char*)U + (off ^ ((row & 7) << 4)));
      }
#pragma unroll
      for (int ni = 0; ni < 5; ++ni)
        bq[ni] = *reinterpret_cast<const s16x8*>(
            &WB1[(wc * 80 + ni * 16 + lr) * 128 + (kk << 5) + (lk << 3)]);
      __builtin_amdgcn_s_setprio(1);
#pragma unroll
      for (int mi = 0; mi < 3; ++mi)
#pragma unroll
        for (int ni = 0; ni < 5; ++ni)
          acc[mi][ni] = __builtin_amdgcn_mfma_f32_16x16x32_bf16(af[mi], bq[ni], acc[mi][ni], 0, 0, 0);
      __builtin_amdgcn_s_setprio(0);
    }
    __syncthreads();
#pragma unroll
    for (int mi = 0; mi < 3; ++mi)
#pragma unroll
      for (int ni = 0; ni < 5; ++ni) {
        int col = wc * 80 + ni * 16 + lr;
#pragma unroll
        for (int r = 0; r < 4; ++r) {
          int row = wr * 48 + mi * 16 + lk * 4 + r;
          U[row * 168 + col] = f2bf(acc[mi][ni][r]);
        }
      }
  }
  __syncthreads();

  {  // cross: 8 threads per b, 2 p's each
    int bl = t >> 3, pj = t & 7;
    int gb = b0 + bl;
    float shcp[2];
#pragma unroll
    for (int q = 0; q < 2; ++q) {
      int p = pj * 2 + q;
      float ax = bf2f(U[(bl * 3 + 0) * 168 + 128 + p]);
      float ay = bf2f(U[(bl * 3 + 1) * 168 + 128 + p]);
      float az = bf2f(U[(bl * 3 + 2) * 168 + 128 + p]);
      float bx = bf2f(U[(bl * 3 + 0) * 168 + 144 + p]);
      float by = bf2f(U[(bl * 3 + 1) * 168 + 144 + p]);
      float bz = bf2f(U[(bl * 3 + 2) * 168 + 144 + p]);
      float cx = ay * bz - az * by;
      float cy = az * bx - ax * bz;
      float cz = ax * by - ay * bx;
      U[(bl * 3 + 0) * 168 + 128 + p] = f2bf(cx);
      U[(bl * 3 + 1) * 168 + 128 + p] = f2bf(cy);
      U[(bl * 3 + 2) * 168 + 128 + p] = f2bf(cz);
      U[(bl * 3 + 0) * 168 + 144 + p] = 0;
      U[(bl * 3 + 1) * 168 + 144 + p] = 0;
      U[(bl * 3 + 2) * 168 + 144 + p] = 0;
      shcp[q] = sqrtf(fmaxf(cx * cx + cy * cy + cz * cz, 1e-8f));
    }
    Ab[(size_t)gb * KP + 640 + pj * 2]     = f2bf(shcp[0]);
    Ab[(size_t)gb * KP + 640 + pj * 2 + 1] = f2bf(shcp[1]);
#pragma unroll
    for (int z = 0; z < 6; ++z)
      Ab[(size_t)gb * KP + 656 + pj * 6 + z] = 0;
  }
  {  // norms k<128 -> Ab cols 512..639
    int bl = t >> 3, kq = t & 7;
    int gb = b0 + bl;
#pragma unroll
    for (int j = 0; j < 2; ++j) {
      int k = kq * 16 + j * 8;
      s16x8 r0 = *(const s16x8*)&U[(bl * 3 + 0) * 168 + k];
      s16x8 r1 = *(const s16x8*)&U[(bl * 3 + 1) * 168 + k];
      s16x8 r2 = *(const s16x8*)&U[(bl * 3 + 2) * 168 + k];
      s16x8 o;
#pragma unroll
      for (int e = 0; e < 8; ++e) {
        float x = bf2f(r0[e]), y = bf2f(r1[e]), z = bf2f(r2[e]);
        o[e] = f2bf(sqrtf(fmaxf(x * x + y * y + z * z, 1e-8f)));
      }
      *(s16x8*)&Ab[(size_t)gb * KP + 512 + k] = o;
    }
  }
  __syncthreads();

  {  // GEMM2: per wave 48x64, acc[3][4]
    f32x4 acc2[3][4];
#pragma unroll
    for (int i = 0; i < 3; ++i)
#pragma unroll
      for (int j = 0; j < 4; ++j) acc2[i][j] = (f32x4){0.f, 0.f, 0.f, 0.f};
#pragma unroll
    for (int kk = 0; kk < 5; ++kk) {
      s16x8 af[3], bq[4];
#pragma unroll
      for (int mi = 0; mi < 3; ++mi) {
        int row = wr * 48 + mi * 16 + lr;
        af[mi] = *(const s16x8*)&U[row * 168 + (kk << 5) + (lk << 3)];
      }
#pragma unroll
      for (int ni = 0; ni < 4; ++ni)
        bq[ni] = *reinterpret_cast<const s16x8*>(
            &WuTp[(wc * 64 + ni * 16 + lr) * 160 + (kk << 5) + (lk << 3)]);
      __builtin_amdgcn_s_setprio(1);
#pragma unroll
      for (int mi = 0; mi < 3; ++mi)
#pragma unroll
        for (int ni = 0; ni < 4; ++ni)
          acc2[mi][ni] = __builtin_amdgcn_mfma_f32_16x16x32_bf16(af[mi], bq[ni], acc2[mi][ni], 0, 0, 0);
      __builtin_amdgcn_s_setprio(0);
    }
#pragma unroll
    for (int mi = 0; mi < 3; ++mi)
#pragma unroll
      for (int ni = 0; ni < 4; ++ni) {
        int col = wc * 64 + ni * 16 + lr;
#pragma unroll
        for (int r = 0; r < 4; ++r) {
          int row = row0 + wr * 48 + mi * 16 + lk * 4 + r;
          Vub[(size_t)row * 128 + col] = f2bf(acc2[mi][ni][r]);
        }
      }
  }

  {  // feats -> Ab[:,0:512) bf16 for this block's 32 rows (coalesced streaming;
     // overlaps other blocks' compute at 4 blocks/CU)
#pragma unroll
    for (int j = 0; j < 8; ++j) {
      int idx = j * 256 + t;               // [0, 2048): 32 rows x 64 chunks
      int bl = idx >> 6, kk = (idx & 63) * 8;
      const float* p = &feats[(size_t)(b0 + bl) * 512 + kk];
      fl4 v0 = *(const fl4*)p, v1 = *(const fl4*)(p + 4);
      *(s16x8*)&Ab[(size_t)(b0 + bl) * KP + kk] = pack8(v0, v1);
    }
  }
}

// ---------------------------------------------------------------------------
// K2: feats_out = silu(Ab @ Wf + bf) -> out f32 + fob bf16.  (R16-exact)
__global__ __launch_bounds__(512, 4) void gemm_feats(
    const short* __restrict__ Ab, const short* __restrict__ WfT,
    const float* __restrict__ bfv, float* __restrict__ out,
    short* __restrict__ fob) {
  const int bid = blockIdx.x;
  const int xcd = bid & 7, bi = bid >> 3;
  const int swz = (xcd < 4 ? xcd * 196 : 784 + (xcd - 4) * 195) + bi;
  const int mt = swz >> 1, nt = swz & 1;
  const int row0 = mt << 7, n0 = nt << 8;
  const int t = threadIdx.x;
  const int lane = t & 63, wv = t >> 6;
  const int wr = wv >> 2, wc = wv & 3;        // 2 x 4 wave grid
  const int lr = lane & 15, lk = lane >> 4;

  __shared__ __align__(16) short S[(128 + 256) * 64];   // 48 KB: As | Bs
  short* As = S;
  short* Bs = S + 128 * 64;

  const short* srcA[2]; int adof[2];
#pragma unroll
  for (int j = 0; j < 2; ++j) {
    int cid = j * 512 + t;
    int row = cid >> 3, ch = cid & 7;
    srcA[j] = &Ab[(size_t)min(row0 + row, BATCH - 1) * KP + (ch ^ (row & 7)) * 8];
    adof[j] = cid * 8;
  }
  const short* srcB[4]; int bdof[4];
#pragma unroll
  for (int j = 0; j < 4; ++j) {
    int cid = j * 512 + t;
    int row = cid >> 3, ch = cid & 7;
    srcB[j] = &WfT[(size_t)(n0 + row) * KP + (ch ^ (row & 7)) * 8];
    bdof[j] = cid * 8;
  }

  f32x4 acc[4][4];
#pragma unroll
  for (int i = 0; i < 4; ++i)
#pragma unroll
    for (int j = 0; j < 4; ++j) acc[i][j] = (f32x4){0.f, 0.f, 0.f, 0.f};

  for (int ks = 0; ks < 11; ++ks) {
    const int k0 = ks << 6;
    __syncthreads();
    glds16(srcA[0] + k0, &As[adof[0]]);
    glds16(srcA[1] + k0, &As[adof[1]]);
#pragma unroll
    for (int j = 0; j < 4; ++j) glds16(srcB[j] + k0, &Bs[bdof[j]]);
    __syncthreads();
#pragma unroll
    for (int kk = 0; kk < 2; ++kk) {
      s16x8 af[4], bq[4];
#pragma unroll
      for (int mi = 0; mi < 4; ++mi) {
        int rw = wr * 64 + mi * 16 + lr;
        af[mi] = *(const s16x8*)&As[rw * 64 + (((kk << 2) + lk) ^ (rw & 7)) * 8];
      }
#pragma unroll
      for (int ni = 0; ni < 4; ++ni) {
        int rn = wc * 64 + ni * 16 + lr;
        bq[ni] = *(const s16x8*)&Bs[rn * 64 + (((kk << 2) + lk) ^ (rn & 7)) * 8];
      }
      __builtin_amdgcn_s_setprio(1);
#pragma unroll
      for (int mi = 0; mi < 4; ++mi)
#pragma unroll
        for (int ni = 0; ni < 4; ++ni)
          acc[mi][ni] = __builtin_amdgcn_mfma_f32_16x16x32_bf16(af[mi], bq[ni], acc[mi][ni], 0, 0, 0);
      __builtin_amdgcn_s_setprio(0);
    }
  }

  // coalesced epilogue: 8 groups of 16 rows staged through LDS
  float* Ls = (float*)S;
#pragma unroll
  for (int g = 0; g < 8; ++g) {
    __syncthreads();
    if (wr == (g >> 2)) {
      int mi = g & 3;
#pragma unroll
      for (int ni = 0; ni < 4; ++ni) {
        int colL = wc * 64 + ni * 16 + lr;
        float bb = bfv[n0 + colL];
#pragma unroll
        for (int rr = 0; rr < 4; ++rr) {
          float x = acc[mi][ni][rr] + bb;
          Ls[(lk * 4 + rr) * 256 + colL] = x / (1.f + __expf(-x));
        }
      }
    }
    __syncthreads();
    {
      int rowL = t >> 5, seg = t & 31;
      int grow = row0 + g * 16 + rowL;
      if (grow < BATCH) {
        const float* p = &Ls[rowL * 256 + seg * 8];
        fl4 a = *(const fl4*)p, b = *(const fl4*)(p + 4);
        float* po = &out[(size_t)grow * 512 + n0 + seg * 8];
        *(fl4*)po = a; *(fl4*)(po + 4) = b;
        *(s16x8*)&fob[(size_t)grow * 512 + n0 + seg * 8] = pack8(a, b);
      }
    }
  }
}

// ---------------------------------------------------------------------------
// K3: gating GEMM + sigmoid*Vub -> vectors_out f32. (R16-exact)
__global__ __launch_bounds__(512, 4) void gemm_gate(
    const short* __restrict__ fob, const short* __restrict__ WgT,
    const float* __restrict__ bg, const short* __restrict__ Vub,
    float* __restrict__ out) {
  const int bid = blockIdx.x;
  const int xcd = bid & 7, bi = bid >> 3;
  const int swz = (xcd < 7 ? xcd * 49 : 343 + (xcd - 7) * 48) + bi;
  const int row0 = swz << 8;
  const int t = threadIdx.x;
  const int lane = t & 63, wv = t >> 6;
  const int wr = wv >> 1, wc = wv & 1;
  const int lr = lane & 15, lk = lane >> 4;

  __shared__ __align__(16) short S[(256 + 128) * 64];
  short* As = S;
  short* Bs = S + 256 * 64;

  const short* srcA[4]; int adof[4];
#pragma unroll
  for (int j = 0; j < 4; ++j) {
    int cid = j * 512 + t;
    int row = cid >> 3, ch = cid & 7;
    srcA[j] = &fob[(size_t)min(row0 + row, BATCH - 1) * 512 + (ch ^ (row & 7)) * 8];
    adof[j] = cid * 8;
  }
  const short* srcB[2]; int bdof[2];
#pragma unroll
  for (int j = 0; j < 2; ++j) {
    int cid = j * 512 + t;
    int row = cid >> 3, ch = cid & 7;
    srcB[j] = &WgT[(size_t)row * 512 + (ch ^ (row & 7)) * 8];
    bdof[j] = cid * 8;
  }

  f32x4 acc[4][4];
#pragma unroll
  for (int i = 0; i < 4; ++i)
#pragma unroll
    for (int j = 0; j < 4; ++j) acc[i][j] = (f32x4){0.f, 0.f, 0.f, 0.f};

  for (int ks = 0; ks < 8; ++ks) {
    const int k0 = ks << 6;
    __syncthreads();
#pragma unroll
    for (int j = 0; j < 4; ++j) glds16(srcA[j] + k0, &As[adof[j]]);
    glds16(srcB[0] + k0, &Bs[bdof[0]]);
    glds16(srcB[1] + k0, &Bs[bdof[1]]);
    __syncthreads();
#pragma unroll
    for (int kk = 0; kk < 2; ++kk) {
      s16x8 af[4], bq[4];
#pragma unroll
      for (int mi = 0; mi < 4; ++mi) {
        int rw = wr * 64 + mi * 16 + lr;
        af[mi] = *(const s16x8*)&As[rw * 64 + (((kk << 2) + lk) ^ (rw & 7)) * 8];
      }
#pragma unroll
      for (int ni = 0; ni < 4; ++ni) {
        int rn = wc * 64 + ni * 16 + lr;
        bq[ni] = *(const s16x8*)&Bs[rn * 64 + (((kk << 2) + lk) ^ (rn & 7)) * 8];
      }
      __builtin_amdgcn_s_setprio(1);
#pragma unroll
      for (int mi = 0; mi < 4; ++mi)
#pragma unroll
        for (int ni = 0; ni < 4; ++ni)
          acc[mi][ni] = __builtin_amdgcn_mfma_f32_16x16x32_bf16(af[mi], bq[ni], acc[mi][ni], 0, 0, 0);
      __builtin_amdgcn_s_setprio(0);
    }
  }

#pragma unroll
  for (int ni = 0; ni < 4; ++ni) {
    int col = wc * 64 + ni * 16 + lr;
    float bb = bg[col];
#pragma unroll
    for (int mi = 0; mi < 4; ++mi) {
      int rbase = row0 + wr * 64 + mi * 16 + lk * 4;
#pragma unroll
      for (int rr = 0; rr < 4; ++rr) {
        int gr = rbase + rr;
        if (gr < BATCH) {
          float x = acc[mi][ni][rr] + bb;
          float gate = 1.f / (1.f + __expf(-x));
          size_t vb = (size_t)(3 * gr) * 128 + col;
          float* po = &out[VECBASE + ((size_t)gr * 128 + col) * 3];
          po[0] = gate * bf2f(Vub[vb]);
          po[1] = gate * bf2f(Vub[vb + 128]);
          po[2] = gate * bf2f(Vub[vb + 256]);
        }
      }
    }
  }
}

// ---------------------------------------------------------------------------
extern "C" void kernel_launch(void* const* d_in, const int* in_sizes, int n_in,
                              void* d_out, int out_size, void* d_ws, size_t ws_size,
                              hipStream_t stream) {
  const float* feats = (const float*)d_in[0];
  const float* vecs  = (const float*)d_in[1];
  const float* Wh    = (const float*)d_in[2];
  const float* Wcp   = (const float*)d_in[3];
  const float* Wu    = (const float*)d_in[4];
  const float* Wf    = (const float*)d_in[5];
  const float* bfv   = (const float*)d_in[6];
  const float* Wg    = (const float*)d_in[7];
  const float* bg    = (const float*)d_in[8];
  float* out = (float*)d_out;

  char* ws = (char*)d_ws;
  short* Ab   = (short*)ws;                                // 140,800,000 B
  short* Vub  = (short*)(ws + 140800000);                  //  76,800,000 B
  short* fob  = (short*)(ws + 217600000);                  // 102,400,000 B
  short* WfT  = (short*)(ws + 320000000);                  //     720,896 B
  short* WgT  = (short*)(ws + 320720896);                  //     131,072 B
  short* WB1  = (short*)(ws + 320851968);                  //      40,960 B
  short* WuTp = (short*)(ws + 320892928);                  //      40,960 B

  hipLaunchKernelGGL(prep_w,     dim3(1824), dim3(256), 0, stream,
                     Wh, Wcp, Wu, Wf, Wg, WB1, WuTp, WfT, WgT);
  hipLaunchKernelGGL(geo_fused,  dim3(3125), dim3(256), 0, stream,
                     vecs, feats, WB1, WuTp, Ab, Vub);
  hipLaunchKernelGGL(gemm_feats, dim3(1564), dim3(512), 0, stream,
                     Ab, WfT, bfv, out, fob);
  hipLaunchKernelGGL(gemm_gate,  dim3(391),  dim3(512), 0, stream,
                     fob, WgT, bg, Vub, out);
}